// Round 1
// 565.071 us; speedup vs baseline: 2.5259x; 2.5259x over previous
//
#include <hip/hip_runtime.h>

#define EPS 1e-6f
#define NSTEPS 4
#define TPB 256
#define TILES 8          // tiles (b,c images) per block; 32 threads per tile
#define PITCH 33         // LDS row pitch (floats): (r+i)%32 bank map, 2-way max => free
#define TSTRIDE (32 * PITCH)

// ---------------------------------------------------------------------------
// Kernel 1: precompute Thomas coefficients per (step, c, solve-line).
// For each step s (t = s*DT) and channel c:
//   x-dir: smooth alpha along w, dt = DT/2;  line index = row h, iter = w
//   y-dir: smooth beta  along h, dt = DT;    line index = col w, iter = h
// Output layout (lane-coalesced for the solver):
//   P[( (s*3 + c)*32 + i )*32 + lane] = float4(a_i, 1/denom_i, cs_i, 0)
// where lane = h (x-dir) or w (y-dir).
// ---------------------------------------------------------------------------
__global__ void coeff_kernel(const float* __restrict__ ab,
                             const float* __restrict__ atc,
                             const float* __restrict__ bb,
                             const float* __restrict__ btc,
                             float4* __restrict__ PX,
                             float4* __restrict__ PY)
{
    int tid = blockIdx.x * blockDim.x + threadIdx.x;
    if (tid >= 768) return;                 // 2 dirs * 4 steps * 3 ch * 32 lanes
    int lane = tid & 31;
    int rest = tid >> 5;                    // 0..23
    int c    = rest % 3;
    int s    = (rest / 3) & 3;
    int dir  = rest / 12;                   // 0 = x, 1 = y
    float t  = 0.15f * (float)s;

    float A[32];
    float dt;
    if (dir == 0) {
        int h = lane;
        const float* pa = ab  + (c * 32 + h) * 32;
        const float* pt = atc + (c * 32 + h) * 32;
        #pragma unroll
        for (int w = 0; w < 32; w++)
            A[w] = fmaxf(pa[w] + t * pt[w], EPS);
        dt = 0.075f;                        // DT/2
    } else {
        int w = lane;
        #pragma unroll
        for (int h = 0; h < 32; h++)
            A[h] = fmaxf(bb[(c * 32 + h) * 32 + w] + t * btc[(c * 32 + h) * 32 + w], EPS);
        dt = 0.15f;                         // DT
    }

    // 3-tap mean with replicate padding
    float S[32];
    #pragma unroll
    for (int i = 0; i < 32; i++) {
        float l = A[(i == 0) ? 0 : i - 1];
        float r = A[(i == 31) ? 31 : i + 1];
        S[i] = (l + A[i] + r) / 3.0f;
    }

    float4* dst = (dir == 0 ? PX : PY) + ((s * 3 + c) * 32) * 32 + lane;
    float cp = 0.0f;
    for (int i = 0; i < 32; i++) {
        float co = S[i] * dt;               // coeff = smoothed * dt / DX^2 (DX=1)
        float a  = -co;
        float b  = (i == 0 || i == 31) ? (1.0f + co) : (1.0f + 2.0f * co);
        float cc = -co;
        float denom = (b - a * cp) + EPS;   // matches ref: eps added every step
        float inv = 1.0f / denom;           // precise division here (cheap)
        float cs  = cc / denom;
        if (i == 31) cs = 0.0f;             // ref zeroes c_star[N-1]
        dst[i * 32] = make_float4(a, inv, cs, 0.0f);
        cp = cs;
    }
}

// ---------------------------------------------------------------------------
// Kernel 2: fully fused 4-step ADI pipeline. One 32-thread group per (b,c)
// tile; the tile lives in LDS across all 12 solves. x-phases: thread = row h,
// serial over w. y-phases: thread = col w, serial over h. Forward-sweep
// intermediates and cs coefficients are kept in registers (val[32], csr[32]);
// x2 -> scale -> next x1 chains in registers with no LDS round trip.
//
// __launch_bounds__(256, 2): 256-VGPR budget. val[]+csr[] = 64 floats live
// simultaneously at every fwd/bwd boundary; the previous (256,4)/128-cap
// build allocated 64 VGPRs and spilled csr[] to scratch (~2.5 GB of HBM
// writes = 13.5x output, the dominant cost). LDS (33.8 KB/block -> 4
// blocks/CU -> 16 waves/CU) caps occupancy anyway, so the extra registers
// are free.
// ---------------------------------------------------------------------------
__global__ __launch_bounds__(TPB, 2)
void diffuse_kernel(const float* __restrict__ u,
                    const float4* __restrict__ PX,
                    const float4* __restrict__ PY,
                    const float* __restrict__ coupling,
                    float* __restrict__ out)
{
    __shared__ float lds[TILES * TSTRIDE];

    const int tid = threadIdx.x;
    const int tl  = tid >> 5;               // tile within block (0..7)
    const int r   = tid & 31;               // lane within tile
    // consecutive blocks share c: co-resident blocks on a CU keep the same
    // 16 KB px + 16 KB py slabs hot in the 32 KB L1 (old %3 mapping mixed
    // 3 channels = 96 KB through L1)
    const int nper = gridDim.x / 3;         // blocks per channel (2048)
    const int c    = blockIdx.x / nper;
    const long grp = blockIdx.x % nper;
    const long b0  = grp * TILES + tl;      // batch index of this tile
    const long base = (b0 * 3 + c) << 10;   // 32*32 floats per tile

    float* T = lds + tl * TSTRIDE;

    // ---- stage global -> LDS (coalesced float4 per half-wave) ----
    const float4* src4 = (const float4*)(u + base);
    #pragma unroll
    for (int j = 0; j < 8; j++) {
        float4 v = src4[j * 32 + r];
        int f = (j * 32 + r) * 4;           // linear float index in tile
        int row = f >> 5, col = f & 31;
        float* p = T + row * PITCH + col;
        p[0] = v.x; p[1] = v.y; p[2] = v.z; p[3] = v.w;
    }
    const float kc = coupling[c * 3 + c];
    __syncthreads();

    float val[32];
    float csr[32];

    #pragma unroll 1
    for (int s = 0; s < NSTEPS; s++) {
        const float4* px = PX + (s * 3 + c) * 1024;
        const float4* py = PY + (s * 3 + c) * 1024;

        // ---------- x half-step #1 (thread = row r) ----------
        {
            float dp = 0.0f;
            #pragma unroll
            for (int i = 0; i < 32; i++) {
                float4 p = px[i * 32 + r];
                float d  = (s == 0) ? T[r * PITCH + i] : val[i];
                dp = (d - p.x * dp) * p.y;
                val[i] = dp;
                csr[i] = p.z;
            }
            float x = 0.0f;
            #pragma unroll
            for (int i = 31; i >= 0; i--) {
                x = val[i] - csr[i] * x;
                T[r * PITCH + i] = x;       // expose rows for y transpose
            }
        }
        __syncthreads();

        // ---------- y full step (thread = col r) ----------
        {
            float dp = 0.0f;
            #pragma unroll
            for (int i = 0; i < 32; i++) {
                float4 p = py[i * 32 + r];
                float d  = T[i * PITCH + r];
                dp = (d - p.x * dp) * p.y;
                val[i] = dp;
                csr[i] = p.z;
            }
            float x = 0.0f;
            #pragma unroll
            for (int i = 31; i >= 0; i--) {
                x = val[i] - csr[i] * x;
                T[i * PITCH + r] = x;       // expose cols for x transpose
            }
        }
        __syncthreads();

        // ---------- x half-step #2 (thread = row r), result + scale in regs ----------
        {
            float dp = 0.0f;
            #pragma unroll
            for (int i = 0; i < 32; i++) {
                float4 p = px[i * 32 + r];
                float d  = T[r * PITCH + i];
                dp = (d - p.x * dp) * p.y;
                val[i] = dp;
                csr[i] = p.z;
            }
            float x = 0.0f;
            #pragma unroll
            for (int i = 31; i >= 0; i--) {
                x = val[i] - csr[i] * x;    // backward uses UNSCALED neighbor
                val[i] = kc * x;            // channel-diagonal scale
            }
        }
        // no barrier needed: x2 and next x1 touch only this thread's row
    }

    // ---- write back: regs -> LDS rows -> coalesced global float4 ----
    #pragma unroll
    for (int i = 0; i < 32; i++) T[r * PITCH + i] = val[i];
    __syncthreads();

    float4* dst4 = (float4*)(out + base);
    #pragma unroll
    for (int j = 0; j < 8; j++) {
        int f = (j * 32 + r) * 4;
        int row = f >> 5, col = f & 31;
        float* p = T + row * PITCH + col;
        dst4[j * 32 + r] = make_float4(p[0], p[1], p[2], p[3]);
    }
}

// ---------------------------------------------------------------------------
extern "C" void kernel_launch(void* const* d_in, const int* in_sizes, int n_in,
                              void* d_out, int out_size, void* d_ws, size_t ws_size,
                              hipStream_t stream) {
    const float* u   = (const float*)d_in[0];
    const float* ab  = (const float*)d_in[1];  // alpha_base
    const float* bb  = (const float*)d_in[2];  // beta_base
    const float* atc = (const float*)d_in[3];  // alpha_time_coeff
    const float* btc = (const float*)d_in[4];  // beta_time_coeff
    const float* cpl = (const float*)d_in[5];  // channel_coupling [3][3]
    float* out = (float*)d_out;

    // workspace: PX (4*3*32*32 float4 = 192 KB) then PY (192 KB)
    float4* PX = (float4*)d_ws;
    float4* PY = PX + 4 * 3 * 32 * 32;

    coeff_kernel<<<3, 256, 0, stream>>>(ab, atc, bb, btc, PX, PY);

    int B = in_sizes[0] / (3 * 32 * 32);       // 16384
    int nblocks = (B / TILES) * 3;             // 6144 blocks of 8 tiles
    diffuse_kernel<<<nblocks, TPB, 0, stream>>>(u, PX, PY, cpl, out);
}